// Round 1
// baseline (13683.565 us; speedup 1.0000x reference)
//
#include <hip/hip_runtime.h>

#define NT 256
#define NB 5          // num heads
#define H 64
#define DIN 100

__global__ __launch_bounds__(NT)
void drnet_kernel(const float* __restrict__ t,
                  const float* __restrict__ x,
                  const float* __restrict__ dW1, const float* __restrict__ db1,
                  const float* __restrict__ dW2, const float* __restrict__ db2,
                  const float* __restrict__ hw1, const float* __restrict__ htw1, const float* __restrict__ hb1,
                  const float* __restrict__ hw2, const float* __restrict__ htw2, const float* __restrict__ hb2,
                  const float* __restrict__ hw3, const float* __restrict__ htw3, const float* __restrict__ hb3,
                  float* __restrict__ out, int N)
{
    __shared__ float sW1[DIN * H];   // 25.6 KB
    __shared__ float sW2[H * H];     // 16 KB
    __shared__ float sb1[H], sb2[H];
    __shared__ int cnt[NB + 1], base_[NB + 1];
    __shared__ unsigned short sperm[NT];

    const int tid = threadIdx.x;

    // ---- stage trunk weights into LDS (coalesced float4) ----
    for (int idx = tid; idx < DIN * H / 4; idx += NT)
        ((float4*)sW1)[idx] = ((const float4*)dW1)[idx];
    for (int idx = tid; idx < H * H / 4; idx += NT)
        ((float4*)sW2)[idx] = ((const float4*)dW2)[idx];
    if (tid < H) { sb1[tid] = db1[tid]; sb2[tid] = db2[tid]; }
    if (tid <= NB) cnt[tid] = 0;
    __syncthreads();

    // ---- in-block sort by head bin so waves get uniform q ----
    const int i0 = blockIdx.x * NT + tid;
    int q0 = NB;   // NB == invalid marker
    if (i0 < N) {
        float tv0 = t[i0];
        int b = (int)floorf(tv0 * 5.0f);
        q0 = min(max(b, 0), NB - 1);
    }
    int pos = atomicAdd(&cnt[q0], 1);
    __syncthreads();
    if (tid == 0) {
        int r = 0;
        #pragma unroll
        for (int b = 0; b <= NB; ++b) { base_[b] = r; r += cnt[b]; }
    }
    __syncthreads();
    sperm[base_[q0] + pos] = (unsigned short)(tid | (q0 << 8));
    __syncthreads();

    const int pk = sperm[tid];
    const int li = pk & 255;
    const int q  = pk >> 8;
    const bool valid = (q < NB);
    const int i  = blockIdx.x * NT + li;
    const int ii = valid ? i : 0;
    const int qq = valid ? q : 0;
    const float tv = t[ii];

    // ---- trunk layer 1: h1 = relu(x @ dW1 + db1) ----
    float ha[H];   // h1, later a1
    float hb_[H];  // h2, later a2
    #pragma unroll
    for (int j = 0; j < H; ++j) ha[j] = sb1[j];

    const float4* xrow = (const float4*)(x + (size_t)ii * DIN);
    #pragma unroll 1
    for (int k4 = 0; k4 < DIN / 4; ++k4) {
        float4 xv = xrow[k4];
        #pragma unroll
        for (int u = 0; u < 4; ++u) {
            const float xk = (u == 0) ? xv.x : (u == 1) ? xv.y : (u == 2) ? xv.z : xv.w;
            const float4* wr = (const float4*)(sW1 + (k4 * 4 + u) * H);
            #pragma unroll
            for (int j4 = 0; j4 < H / 4; ++j4) {
                float4 w = wr[j4];
                ha[j4 * 4 + 0] += xk * w.x;
                ha[j4 * 4 + 1] += xk * w.y;
                ha[j4 * 4 + 2] += xk * w.z;
                ha[j4 * 4 + 3] += xk * w.w;
            }
        }
    }
    #pragma unroll
    for (int j = 0; j < H; ++j) ha[j] = fmaxf(ha[j], 0.0f);

    // ---- trunk layer 2: h2 = relu(h1 @ dW2 + db2) ----
    #pragma unroll
    for (int j = 0; j < H; ++j) hb_[j] = sb2[j];
    #pragma unroll   // FULL unroll: k must be compile-time (register-array index)
    for (int k = 0; k < H; ++k) {
        const float xk = ha[k];
        const float4* wr = (const float4*)(sW2 + k * H);
        #pragma unroll
        for (int j4 = 0; j4 < H / 4; ++j4) {
            float4 w = wr[j4];
            hb_[j4 * 4 + 0] += xk * w.x;
            hb_[j4 * 4 + 1] += xk * w.y;
            hb_[j4 * 4 + 2] += xk * w.z;
            hb_[j4 * 4 + 3] += xk * w.w;
        }
    }
    #pragma unroll
    for (int j = 0; j < H; ++j) hb_[j] = fmaxf(hb_[j], 0.0f);

    // ---- head layer 1: a1 = relu(h2 @ hw1[q] + t*htw1[q] + hb1[q]) ----
    const float* w1q  = hw1  + (size_t)qq * H * H;
    const float* tw1q = htw1 + (size_t)qq * H;
    const float* b1q  = hb1  + (size_t)qq * H;
    #pragma unroll
    for (int j4 = 0; j4 < H / 4; ++j4) {
        float4 b  = ((const float4*)b1q)[j4];
        float4 tw = ((const float4*)tw1q)[j4];
        ha[j4 * 4 + 0] = b.x + tv * tw.x;
        ha[j4 * 4 + 1] = b.y + tv * tw.y;
        ha[j4 * 4 + 2] = b.z + tv * tw.z;
        ha[j4 * 4 + 3] = b.w + tv * tw.w;
    }
    #pragma unroll
    for (int k = 0; k < H; ++k) {
        const float xk = hb_[k];
        const float4* wr = (const float4*)(w1q + k * H);
        #pragma unroll
        for (int j4 = 0; j4 < H / 4; ++j4) {
            float4 w = wr[j4];
            ha[j4 * 4 + 0] += xk * w.x;
            ha[j4 * 4 + 1] += xk * w.y;
            ha[j4 * 4 + 2] += xk * w.z;
            ha[j4 * 4 + 3] += xk * w.w;
        }
    }
    #pragma unroll
    for (int j = 0; j < H; ++j) ha[j] = fmaxf(ha[j], 0.0f);

    // ---- head layer 2: a2 = relu(a1 @ hw2[q] + t*htw2[q] + hb2[q]) ----
    const float* w2q  = hw2  + (size_t)qq * H * H;
    const float* tw2q = htw2 + (size_t)qq * H;
    const float* b2q  = hb2  + (size_t)qq * H;
    #pragma unroll
    for (int j4 = 0; j4 < H / 4; ++j4) {
        float4 b  = ((const float4*)b2q)[j4];
        float4 tw = ((const float4*)tw2q)[j4];
        hb_[j4 * 4 + 0] = b.x + tv * tw.x;
        hb_[j4 * 4 + 1] = b.y + tv * tw.y;
        hb_[j4 * 4 + 2] = b.z + tv * tw.z;
        hb_[j4 * 4 + 3] = b.w + tv * tw.w;
    }
    #pragma unroll
    for (int k = 0; k < H; ++k) {
        const float xk = ha[k];
        const float4* wr = (const float4*)(w2q + k * H);
        #pragma unroll
        for (int j4 = 0; j4 < H / 4; ++j4) {
            float4 w = wr[j4];
            hb_[j4 * 4 + 0] += xk * w.x;
            hb_[j4 * 4 + 1] += xk * w.y;
            hb_[j4 * 4 + 2] += xk * w.z;
            hb_[j4 * 4 + 3] += xk * w.w;
        }
    }
    #pragma unroll
    for (int j = 0; j < H; ++j) hb_[j] = fmaxf(hb_[j], 0.0f);

    // ---- head layer 3: out = a2 @ hw3[q] + t*htw3[q] + hb3[q] ----
    const float* w3q = hw3 + (size_t)qq * H;
    float res = hb3[qq] + tv * htw3[qq];
    #pragma unroll
    for (int k4 = 0; k4 < H / 4; ++k4) {
        float4 w = ((const float4*)w3q)[k4];
        res += hb_[k4 * 4 + 0] * w.x;
        res += hb_[k4 * 4 + 1] * w.y;
        res += hb_[k4 * 4 + 2] * w.z;
        res += hb_[k4 * 4 + 3] * w.w;
    }

    if (valid) out[i] = res;
}

extern "C" void kernel_launch(void* const* d_in, const int* in_sizes, int n_in,
                              void* d_out, int out_size, void* d_ws, size_t ws_size,
                              hipStream_t stream) {
    const float* t    = (const float*)d_in[0];
    const float* x    = (const float*)d_in[1];
    const float* dW1  = (const float*)d_in[2];
    const float* db1  = (const float*)d_in[3];
    const float* dW2  = (const float*)d_in[4];
    const float* db2  = (const float*)d_in[5];
    const float* hw1  = (const float*)d_in[6];
    const float* htw1 = (const float*)d_in[7];
    const float* hb1  = (const float*)d_in[8];
    const float* hw2  = (const float*)d_in[9];
    const float* htw2 = (const float*)d_in[10];
    const float* hb2  = (const float*)d_in[11];
    const float* hw3  = (const float*)d_in[12];
    const float* htw3 = (const float*)d_in[13];
    const float* hb3  = (const float*)d_in[14];
    float* out = (float*)d_out;

    const int N = in_sizes[0];
    const int grid = (N + NT - 1) / NT;

    drnet_kernel<<<grid, NT, 0, stream>>>(t, x, dW1, db1, dW2, db2,
                                          hw1, htw1, hb1, hw2, htw2, hb2,
                                          hw3, htw3, hb3, out, N);
}

// Round 2
// 182.141 us; speedup vs baseline: 75.1261x; 75.1261x over previous
//
#include <hip/hip_runtime.h>

typedef _Float16 f16;
typedef _Float16 f16x8 __attribute__((ext_vector_type(8)));
typedef float f32x4 __attribute__((ext_vector_type(4)));

#define NB 5
#define H 64
#define DIN 100
#define NT 256
#define MAIN_BLOCKS 512

// packed weight-fragment regions in d_ws, units of 16B frags
#define FR_W1   0      // 4 ksteps * 4 mtiles * 64 lanes = 1024 frags
#define FR_W2   1024   // 2 * 4 * 64 = 512
#define FR_HD   1536   // (q*2+layer)*512 + (s*4+mt)*64 + lane ; 5*2*512 = 5120
#define FR_TOT  6656

// Pack weights into MFMA A-operand fragment layout for the transposed compute:
// A = W^T tile: lane l holds W[k=32s+8*(l>>4)+e][16*mt + (l&15)], e=0..7.
__global__ __launch_bounds__(256)
void prepack_kernel(const float* __restrict__ dW1, const float* __restrict__ dW2,
                    const float* __restrict__ hw1, const float* __restrict__ hw2,
                    f16x8* __restrict__ pw)
{
    int F = blockIdx.x * 256 + threadIdx.x;
    if (F >= FR_TOT) return;
    int lane = F & 63, g = lane >> 4, c = lane & 15;
    const float* src;
    int s, mt, kmax;
    if (F < FR_W2) {                       // trunk W1 [100][64], zero-pad K to 128
        int r = F; s = r >> 8; mt = (r >> 6) & 3; src = dW1; kmax = 100;
    } else if (F < FR_HD) {                // trunk W2 [64][64]
        int r = F - FR_W2; s = r >> 8; mt = (r >> 6) & 3; src = dW2; kmax = 64;
    } else {                               // heads hw1/hw2 [5][64][64]
        int r = F - FR_HD; int ql = r >> 9; int q = ql >> 1; int l = ql & 1;
        int r2 = r & 511; s = r2 >> 8; mt = (r2 >> 6) & 3;
        src = (l ? hw2 : hw1) + q * 64 * 64; kmax = 64;
    }
    f16x8 v;
    #pragma unroll
    for (int e = 0; e < 8; ++e) {
        int k = 32 * s + 8 * g + e;
        int m = 16 * mt + c;
        float val = (k < kmax) ? src[k * 64 + m] : 0.0f;
        v[e] = (f16)val;
    }
    pw[F] = v;
}

__device__ __forceinline__ f32x4 mfma16(f16x8 a, f16x8 b, f32x4 c) {
    return __builtin_amdgcn_mfma_f32_16x16x32_f16(a, b, c, 0, 0, 0);
}

__global__ __launch_bounds__(NT, 2)
void drnet_main(const float* __restrict__ t, const float* __restrict__ x,
                const float* __restrict__ db1, const float* __restrict__ db2,
                const float* __restrict__ hb1, const float* __restrict__ htw1,
                const float* __restrict__ hb2, const float* __restrict__ htw2,
                const float* __restrict__ hw3, const float* __restrict__ htw3,
                const float* __restrict__ hb3,
                const f16x8* __restrict__ pw,
                float* __restrict__ out, int N, int nch)
{
    __shared__ float sb1f[H], sb2f[H];
    __shared__ float shb1[NB * H], shw1t[NB * H], shb2[NB * H], shw2t[NB * H], sw3f[NB * H];
    __shared__ float shtw3[NB], shb3[NB];
    __shared__ unsigned char sli[NT], sqv[NT];
    __shared__ float stv[NT];
    __shared__ int scnt[NB + 1], sbase[NB + 1];
    __shared__ __align__(16) unsigned char hbuf[4][2][2048];  // per-wave [16][64] f16, XOR-swizzled

    const int tid = threadIdx.x;
    const int lane = tid & 63;
    const int wv = tid >> 6;
    const int g = lane >> 4;
    const int row = lane & 15;

    // one-time per block: stage fp32 biases/t-weights/w3 into LDS
    for (int p = tid; p < H; p += NT) { sb1f[p] = db1[p]; sb2f[p] = db2[p]; }
    for (int p = tid; p < NB * H; p += NT) {
        shb1[p] = hb1[p];  shw1t[p] = htw1[p];
        shb2[p] = hb2[p];  shw2t[p] = htw2[p];
        sw3f[p] = hw3[p];
    }
    if (tid < NB) { shtw3[tid] = htw3[tid]; shb3[tid] = hb3[tid]; }

    // hoist trunk weight frags into registers (96 VGPR, reused every tile)
    f16x8 w1f[16], w2f[8];
    #pragma unroll
    for (int u = 0; u < 16; ++u) w1f[u] = pw[FR_W1 + u * 64 + lane];
    #pragma unroll
    for (int u = 0; u < 8; ++u)  w2f[u] = pw[FR_W2 + u * 64 + lane];

    for (int ch = blockIdx.x; ch < nch; ch += MAIN_BLOCKS) {
        __syncthreads();   // protect sort arrays from previous chunk's readers
        if (tid <= NB) scnt[tid] = 0;
        __syncthreads();
        const int i0 = ch * NT + tid;
        int q0 = NB; float tv0 = 0.f;
        if (i0 < N) {
            tv0 = t[i0];
            int b = (int)floorf(tv0 * 5.0f);
            q0 = min(max(b, 0), NB - 1);
        }
        int pos = atomicAdd(&scnt[q0], 1);
        __syncthreads();
        if (tid == 0) {
            int r = 0;
            #pragma unroll
            for (int b = 0; b <= NB; ++b) { sbase[b] = r; r += scnt[b]; }
        }
        __syncthreads();
        int sp = sbase[q0] + pos;
        sli[sp] = (unsigned char)tid; sqv[sp] = (unsigned char)q0; stv[sp] = tv0;
        __syncthreads();

        // wave wv owns sorted tiles 4wv..4wv+3 (16 rows each)
        for (int j = 0; j < 4; ++j) {
            const int p0 = (wv * 4 + j) * 16;
            const int qlo = sqv[p0];
            if (qlo >= NB) continue;                       // whole tile is padding
            const int qhi = min((int)sqv[p0 + 15], NB - 1);
            const int li = sli[p0 + row];
            const int rq = sqv[p0 + row];
            const float rt = stv[p0 + row];
            const int iv = (rq < NB) ? (ch * NT + li) : (ch * NT);

            // ---- trunk L1: h1^T = W1^T x^T ---- (K=100 padded to 128)
            const float4* x4 = (const float4*)(x + (size_t)iv * DIN);  // row base 16B-aligned (400=25*16)
            f16x8 xf[4];
            #pragma unroll
            for (int s = 0; s < 3; ++s) {
                float4 a = x4[8 * s + 2 * g];
                float4 b = x4[8 * s + 2 * g + 1];
                xf[s][0] = (f16)a.x; xf[s][1] = (f16)a.y; xf[s][2] = (f16)a.z; xf[s][3] = (f16)a.w;
                xf[s][4] = (f16)b.x; xf[s][5] = (f16)b.y; xf[s][6] = (f16)b.z; xf[s][7] = (f16)b.w;
            }
            {
                float4 a = make_float4(0.f, 0.f, 0.f, 0.f);
                if (g == 0) a = x4[24];                    // k=96..99
                xf[3][0] = (f16)a.x; xf[3][1] = (f16)a.y; xf[3][2] = (f16)a.z; xf[3][3] = (f16)a.w;
                xf[3][4] = (f16)0.f; xf[3][5] = (f16)0.f; xf[3][6] = (f16)0.f; xf[3][7] = (f16)0.f;
            }
            const f32x4 zero = {0.f, 0.f, 0.f, 0.f};
            f32x4 acc[4] = {zero, zero, zero, zero};
            #pragma unroll
            for (int s = 0; s < 4; ++s)
                #pragma unroll
                for (int mt = 0; mt < 4; ++mt)
                    acc[mt] = mfma16(w1f[s * 4 + mt], xf[s], acc[mt]);

            unsigned char* hA = hbuf[wv][0];
            unsigned char* hB = hbuf[wv][1];
            // lane holds h[row][16mt+4g+reg] -> b64 write, XOR-swizzled
            #pragma unroll
            for (int mt = 0; mt < 4; ++mt) {
                const float* bb = &sb1f[16 * mt + 4 * g];
                union { f16 h[4]; unsigned long long u; } pk;
                #pragma unroll
                for (int r2 = 0; r2 < 4; ++r2) pk.h[r2] = (f16)fmaxf(acc[mt][r2] + bb[r2], 0.f);
                *(unsigned long long*)(hA + ((row * 128 + 32 * mt + 8 * g) ^ ((row & 7) << 4))) = pk.u;
            }

            // ---- trunk L2: h2^T = W2^T h1^T ----
            f32x4 acc2[4] = {zero, zero, zero, zero};
            #pragma unroll
            for (int s = 0; s < 2; ++s) {
                f16x8 hf = *(const f16x8*)(hA + ((row * 128 + 64 * s + 16 * g) ^ ((row & 7) << 4)));
                #pragma unroll
                for (int mt = 0; mt < 4; ++mt)
                    acc2[mt] = mfma16(w2f[s * 4 + mt], hf, acc2[mt]);
            }
            #pragma unroll
            for (int mt = 0; mt < 4; ++mt) {
                const float* bb = &sb2f[16 * mt + 4 * g];
                union { f16 h[4]; unsigned long long u; } pk;
                #pragma unroll
                for (int r2 = 0; r2 < 4; ++r2) pk.h[r2] = (f16)fmaxf(acc2[mt][r2] + bb[r2], 0.f);
                *(unsigned long long*)(hB + ((row * 128 + 32 * mt + 8 * g) ^ ((row & 7) << 4))) = pk.u;
            }

            // ---- heads (usually 1, >1 only at sorted-bucket boundary tiles) ----
            #pragma unroll 1
            for (int q = qlo; q <= qhi; ++q) {
                const f16x8* ph1 = pw + FR_HD + (q * 2 + 0) * 512;
                const f16x8* ph2 = pw + FR_HD + (q * 2 + 1) * 512;

                f32x4 a1[4] = {zero, zero, zero, zero};
                #pragma unroll
                for (int s = 0; s < 2; ++s) {
                    f16x8 hf = *(const f16x8*)(hB + ((row * 128 + 64 * s + 16 * g) ^ ((row & 7) << 4)));
                    #pragma unroll
                    for (int mt = 0; mt < 4; ++mt)
                        a1[mt] = mfma16(ph1[(s * 4 + mt) * 64 + lane], hf, a1[mt]);
                }
                #pragma unroll
                for (int mt = 0; mt < 4; ++mt) {
                    const float* bb = &shb1[q * 64 + 16 * mt + 4 * g];
                    const float* tw = &shw1t[q * 64 + 16 * mt + 4 * g];
                    union { f16 h[4]; unsigned long long u; } pk;
                    #pragma unroll
                    for (int r2 = 0; r2 < 4; ++r2)
                        pk.h[r2] = (f16)fmaxf(a1[mt][r2] + bb[r2] + rt * tw[r2], 0.f);
                    *(unsigned long long*)(hA + ((row * 128 + 32 * mt + 8 * g) ^ ((row & 7) << 4))) = pk.u;
                }

                f32x4 a2[4] = {zero, zero, zero, zero};
                #pragma unroll
                for (int s = 0; s < 2; ++s) {
                    f16x8 hf = *(const f16x8*)(hA + ((row * 128 + 64 * s + 16 * g) ^ ((row & 7) << 4)));
                    #pragma unroll
                    for (int mt = 0; mt < 4; ++mt)
                        a2[mt] = mfma16(ph2[(s * 4 + mt) * 64 + lane], hf, a2[mt]);
                }

                // final layer in fp32 VALU: out[row] = sum_c relu(a2)[row][c]*w3[c] + t*tw3 + b3
                float partial = 0.f;
                #pragma unroll
                for (int mt = 0; mt < 4; ++mt) {
                    const float* bb = &shb2[q * 64 + 16 * mt + 4 * g];
                    const float* tw = &shw2t[q * 64 + 16 * mt + 4 * g];
                    const float* w3 = &sw3f[q * 64 + 16 * mt + 4 * g];
                    #pragma unroll
                    for (int r2 = 0; r2 < 4; ++r2) {
                        float v = fmaxf(a2[mt][r2] + bb[r2] + rt * tw[r2], 0.f);
                        partial += v * w3[r2];
                    }
                }
                partial += __shfl_xor(partial, 16, 64);
                partial += __shfl_xor(partial, 32, 64);
                if (lane < 16 && rq == q) {
                    out[ch * NT + li] = partial + rt * shtw3[q] + shb3[q];
                }
            }
        }
    }
}

extern "C" void kernel_launch(void* const* d_in, const int* in_sizes, int n_in,
                              void* d_out, int out_size, void* d_ws, size_t ws_size,
                              hipStream_t stream) {
    const float* t    = (const float*)d_in[0];
    const float* x    = (const float*)d_in[1];
    const float* dW1  = (const float*)d_in[2];
    const float* db1  = (const float*)d_in[3];
    const float* dW2  = (const float*)d_in[4];
    const float* db2  = (const float*)d_in[5];
    const float* hw1  = (const float*)d_in[6];
    const float* htw1 = (const float*)d_in[7];
    const float* hb1  = (const float*)d_in[8];
    const float* hw2  = (const float*)d_in[9];
    const float* htw2 = (const float*)d_in[10];
    const float* hb2  = (const float*)d_in[11];
    const float* hw3  = (const float*)d_in[12];
    const float* htw3 = (const float*)d_in[13];
    const float* hb3  = (const float*)d_in[14];
    float* out = (float*)d_out;

    const int N = in_sizes[0];
    const int nch = (N + NT - 1) / NT;
    f16x8* pw = (f16x8*)d_ws;   // 6656 * 16 B = 104 KiB of scratch

    prepack_kernel<<<(FR_TOT + 255) / 256, 256, 0, stream>>>(dW1, dW2, hw1, hw2, pw);
    drnet_main<<<MAIN_BLOCKS, NT, 0, stream>>>(t, x, db1, db2, hb1, htw1, hb2, htw2,
                                               hw3, htw3, hb3, pw, out, N, nch);
}